// Round 1
// baseline (765.749 us; speedup 1.0000x reference)
//
#include <hip/hip_runtime.h>
#include <math.h>

#define NN 20000      // nodes
#define ER 640000     // raw edges
#define ET 660000     // edges incl. self loops
#define HH 2          // heads
#define C1V 64
#define D1 128        // HH*C1V
#define C2V 128
#define D2 256        // HH*C2V
#define EPSV 1e-5f
#define SLOPE 0.2f

// ---------- helpers ----------

__device__ __forceinline__ void atomicMaxF(float* a, float v) {
  // standard mixed-sign float atomic max via int/uint ordering
  if (v >= 0.f) atomicMax((int*)a, __float_as_int(v));
  else          atomicMin((unsigned int*)a, __float_as_uint(v));
}

__device__ __forceinline__ void edge_sd(const void* ei, int is64, int i, int& s, int& d) {
  if (is64) {
    const long long* p = (const long long*)ei;
    s = (int)p[i]; d = (int)p[ER + i];
  } else {
    const int* p = (const int*)ei;
    s = p[i]; d = p[ER + i];
  }
  s = (s < 0) ? 0 : (s >= NN ? NN - 1 : s);   // crash guard only
  d = (d < 0) ? 0 : (d >= NN ? NN - 1 : d);
}

// ---------- dtype detect: int64 edge_index has all-zero high int32 words ----------
__global__ void k_detect(const int* ei, int* flag) {
  __shared__ int any;
  if (threadIdx.x == 0) any = 0;
  __syncthreads();
  int t = threadIdx.x;
  int v = ei[2*t+1] | ei[2*(t+256)+1] | ei[2*(t+512)+1] | ei[2*(t+768)+1];
  if (v != 0) atomicOr(&any, 1);
  __syncthreads();
  if (t == 0) *flag = (any == 0) ? 1 : 0;   // 1 => int64
}

// ---------- init ----------
__global__ void k_init(float* m1, float* z1, float* as1, float* ad1,
                       float* m2, float* z2, float* as2, float* ad2,
                       int* deg, float* bns1, float* bnq1, float* bns2, float* bnq2) {
  int i = blockIdx.x*blockDim.x + threadIdx.x;
  if (i < NN) {
    deg[i] = 1;   // self loop pre-counted
    #pragma unroll
    for (int h = 0; h < HH; h++) {
      m1[i*HH+h] = -INFINITY; z1[i*HH+h] = 0.f; as1[i*HH+h] = 0.f; ad1[i*HH+h] = 0.f;
      m2[i*HH+h] = -INFINITY; z2[i*HH+h] = 0.f; as2[i*HH+h] = 0.f; ad2[i*HH+h] = 0.f;
    }
  }
  if (i < D1) { bns1[i] = 0.f; bnq1[i] = 0.f; }
  if (i < D2) { bns2[i] = 0.f; bnq2[i] = 0.f; }
}

// ---------- CSR build ----------
__global__ void k_degree(const void* ei, const int* flag, int* deg) {
  int i = blockIdx.x*blockDim.x + threadIdx.x;
  if (i >= ER) return;
  int s, d; edge_sd(ei, *flag, i, s, d);
  atomicAdd(&deg[d], 1);
}

__global__ void k_scan1(const int* deg, int* offs, int* bsum) {
  __shared__ int sm[512];
  int t = threadIdx.x;
  int i = blockIdx.x*512 + t;
  int v = (i < NN) ? deg[i] : 0;
  sm[t] = v;
  __syncthreads();
  for (int o = 1; o < 512; o <<= 1) {
    int add = (t >= o) ? sm[t-o] : 0;
    __syncthreads();
    sm[t] += add;
    __syncthreads();
  }
  if (i < NN) offs[i] = sm[t] - v;          // block-local exclusive
  if (t == 511) bsum[blockIdx.x] = sm[511];
}

__global__ void k_scan2(int* bsum) {
  __shared__ int sm[64];
  int t = threadIdx.x;
  int v = (t < 40) ? bsum[t] : 0;
  sm[t] = v;
  __syncthreads();
  for (int o = 1; o < 64; o <<= 1) {
    int add = (t >= o) ? sm[t-o] : 0;
    __syncthreads();
    sm[t] += add;
    __syncthreads();
  }
  if (t < 40) bsum[t] = sm[t] - v;          // exclusive over block sums
}

__global__ void k_scan3(int* offs, const int* bsum, int* cursor) {
  int i = blockIdx.x*blockDim.x + threadIdx.x;
  if (i < NN) {
    int o = offs[i] + bsum[i >> 9];
    offs[i] = o;
    cursor[i] = o;
  }
  if (i == 0) offs[NN] = ET;
}

__global__ void k_scatter(const void* ei, const int* flag, int* cursor, int* eids, int* srcs) {
  int i = blockIdx.x*blockDim.x + threadIdx.x;
  if (i >= ET) return;
  int s, d;
  if (i < ER) edge_sd(ei, *flag, i, s, d); else { s = d = i - ER; }
  int pos = atomicAdd(&cursor[d], 1);
  eids[pos] = i;
  srcs[pos] = s;
}

// ---------- GEMM1: [NN,64] @ [64,128] ----------
__global__ __launch_bounds__(256) void k_gemm1(const float* x, const float* W, float* hx) {
  __shared__ float Wl[64*128];   // 32 KB
  __shared__ float xs[8][64];    // 2 KB
  int t = threadIdx.x;
  const float4* W4 = (const float4*)W;
  float4* Wl4 = (float4*)Wl;
  for (int i = t; i < 64*128/4; i += 256) Wl4[i] = W4[i];
  int r0 = blockIdx.x * 8;
  const float4* x4 = (const float4*)(x + (size_t)r0*64);
  float4* xs4 = (float4*)&xs[0][0];
  if (t < 128) xs4[t] = x4[t];
  __syncthreads();
  int j = t & 127, g = t >> 7;               // g selects rows g*4..g*4+3
  float a0=0.f, a1=0.f, a2=0.f, a3=0.f;
  for (int k = 0; k < 64; k++) {
    float w = Wl[k*128 + j];
    a0 += xs[g*4+0][k]*w;
    a1 += xs[g*4+1][k]*w;
    a2 += xs[g*4+2][k]*w;
    a3 += xs[g*4+3][k]*w;
  }
  int r = r0 + g*4;
  hx[(size_t)(r+0)*128 + j] = a0;
  hx[(size_t)(r+1)*128 + j] = a1;
  hx[(size_t)(r+2)*128 + j] = a2;
  hx[(size_t)(r+3)*128 + j] = a3;
}

// ---------- GEMM2: [NN,128] @ [128,256], k-chunked W in LDS ----------
__global__ __launch_bounds__(256) void k_gemm2(const float* h1, const float* W, float* hx) {
  __shared__ float Wl[32*256];   // 32 KB per chunk
  __shared__ float xs[16][128];  // 8 KB
  int t = threadIdx.x;
  int r0 = blockIdx.x * 16;
  const float4* x4 = (const float4*)(h1 + (size_t)r0*128);
  float4* xs4 = (float4*)&xs[0][0];
  for (int i = t; i < 16*128/4; i += 256) xs4[i] = x4[i];
  float acc[16];
  #pragma unroll
  for (int r = 0; r < 16; r++) acc[r] = 0.f;
  const float4* W4 = (const float4*)W;
  float4* Wl4 = (float4*)Wl;
  for (int kc = 0; kc < 4; kc++) {
    __syncthreads();
    for (int i = t; i < 32*256/4; i += 256) Wl4[i] = W4[kc*(32*256/4) + i];
    __syncthreads();
    for (int k = 0; k < 32; k++) {
      float w = Wl[k*256 + t];
      int kk = kc*32 + k;
      #pragma unroll
      for (int r = 0; r < 16; r++) acc[r] += xs[r][kk]*w;
    }
  }
  #pragma unroll
  for (int r = 0; r < 16; r++) hx[(size_t)(r0+r)*256 + t] = acc[r];
}

// ---------- attention scalars: a_s[n,h], a_d[n,h] ----------
template<int C>
__global__ void k_att(const float* hx, const float* att_s, const float* att_d,
                      float* a_s, float* a_d) {
  int n = blockIdx.x;
  int t = threadIdx.x;           // blockDim = HH*C
  int h = t / C, c = t % C;
  float v = hx[(size_t)n*(HH*C) + t];
  float ps = v * att_s[h*C + c];
  float pd = v * att_d[h*C + c];
  #pragma unroll
  for (int o = 32; o; o >>= 1) { ps += __shfl_down(ps, o); pd += __shfl_down(pd, o); }
  if ((t & 63) == 0) {
    atomicAdd(&a_s[n*HH + h], ps);
    atomicAdd(&a_d[n*HH + h], pd);
  }
}

// ---------- edge pass A: e = leakyrelu(a_s[src]+a_d[dst]); segment max ----------
__global__ void k_edge_a(const void* ei, const int* flag, const float* a_s, const float* a_d,
                         float* ev, float* m) {
  int i = blockIdx.x*blockDim.x + threadIdx.x;
  if (i >= ET) return;
  int s, d;
  if (i < ER) edge_sd(ei, *flag, i, s, d); else { s = d = i - ER; }
  #pragma unroll
  for (int h = 0; h < HH; h++) {
    float e = a_s[s*HH + h] + a_d[d*HH + h];
    e = (e > 0.f) ? e : SLOPE * e;
    ev[(size_t)i*HH + h] = e;
    atomicMaxF(&m[d*HH + h], e);
  }
}

// ---------- edge pass B: p = exp(e - m[dst]); segment sum ----------
__global__ void k_edge_b(const void* ei, const int* flag, const float* m,
                         float* ev, float* z) {
  int i = blockIdx.x*blockDim.x + threadIdx.x;
  if (i >= ET) return;
  int s, d;
  if (i < ER) edge_sd(ei, *flag, i, s, d); else { s = d = i - ER; }
  #pragma unroll
  for (int h = 0; h < HH; h++) {
    float p = expf(ev[(size_t)i*HH + h] - m[d*HH + h]);
    ev[(size_t)i*HH + h] = p;
    atomicAdd(&z[d*HH + h], p);
  }
}

// ---------- aggregation: out[n] = sum_e p*hx[src] / z + bias ----------
template<int C>
__global__ void k_agg(const int* offs, const int* eids, const int* srcs,
                      const float* p, const float* z, const float* hx,
                      const float* bias, float* out) {
  int n = blockIdx.x;
  int t = threadIdx.x;           // blockDim = HH*C
  int h = t / C, c = t % C;
  int beg = offs[n], end = offs[n+1];
  float acc = 0.f;
  for (int j = beg; j < end; j++) {
    int eid = eids[j];
    int s   = srcs[j];
    float pv = p[(size_t)eid*HH + h];
    acc += pv * hx[(size_t)s*(HH*C) + h*C + c];
  }
  out[(size_t)n*(HH*C) + t] = acc / z[n*HH + h] + bias[t];
}

// ---------- batchnorm stats ----------
template<int D>
__global__ void k_bnstats(const float* x, float* bnsum, float* bnsq) {
  const int ROWS = 100;          // grid = 200 blocks, block = D threads
  int c = threadIdx.x;
  int r0 = blockIdx.x * ROWS;
  float s = 0.f, s2 = 0.f;
  for (int r = 0; r < ROWS; r++) {
    float v = x[(size_t)(r0 + r)*D + c];
    s += v; s2 += v*v;
  }
  atomicAdd(&bnsum[c], s);
  atomicAdd(&bnsq[c], s2);
}

// ---------- batchnorm apply + ReLU ----------
template<int D>
__global__ void k_bnapply(const float* x, const float* bnsum, const float* bnsq,
                          const float* gamma, const float* beta, float* out) {
  int i = blockIdx.x*blockDim.x + threadIdx.x;
  if (i >= NN*D) return;
  int c = i & (D-1);
  float mean = bnsum[c] * (1.f/NN);
  float var  = bnsq[c] * (1.f/NN) - mean*mean;
  float v = (x[i] - mean) * rsqrtf(var + EPSV) * gamma[c] + beta[c];
  out[i] = v > 0.f ? v : 0.f;
}

// ---------- launcher ----------
extern "C" void kernel_launch(void* const* d_in, const int* in_sizes, int n_in,
                              void* d_out, int out_size, void* d_ws, size_t ws_size,
                              hipStream_t stream) {
  const float* x      = (const float*)d_in[0];
  const void*  ei     = d_in[1];
  const float* W1     = (const float*)d_in[2];
  const float* att_s1 = (const float*)d_in[3];
  const float* att_d1 = (const float*)d_in[4];
  const float* bias1  = (const float*)d_in[5];
  const float* gamma1 = (const float*)d_in[6];
  const float* beta1  = (const float*)d_in[7];
  const float* W2     = (const float*)d_in[8];
  const float* att_s2 = (const float*)d_in[9];
  const float* att_d2 = (const float*)d_in[10];
  const float* bias2  = (const float*)d_in[11];
  const float* gamma2 = (const float*)d_in[12];
  const float* beta2  = (const float*)d_in[13];

  // workspace layout (floats then ints); out2 aliases hx1+out1 (both dead by then)
  float* fws  = (float*)d_ws;
  float* hx1  = fws;                         // NN*D1
  float* out1 = hx1 + (size_t)NN*D1;         // NN*D1
  float* out2 = hx1;                         // NN*D2 (alias)
  float* h1   = out1 + (size_t)NN*D1;        // NN*D1
  float* hx2  = h1  + (size_t)NN*D1;         // NN*D2
  float* ev   = hx2 + (size_t)NN*D2;         // ET*HH (reused per layer)
  float* as1  = ev  + (size_t)ET*HH;
  float* ad1  = as1 + NN*HH;
  float* m1   = ad1 + NN*HH;
  float* z1   = m1  + NN*HH;
  float* as2  = z1  + NN*HH;
  float* ad2  = as2 + NN*HH;
  float* m2   = ad2 + NN*HH;
  float* z2   = m2  + NN*HH;
  float* bns1 = z2  + NN*HH;                 // D1
  float* bnq1 = bns1 + D1;
  float* bns2 = bnq1 + D1;                   // D2
  float* bnq2 = bns2 + D2;
  int* ip     = (int*)(bnq2 + D2);
  int* flag   = ip; ip += 16;
  int* deg    = ip; ip += NN;
  int* offs   = ip; ip += NN + 1;
  int* bsum   = ip; ip += 64;
  int* cursor = ip; ip += NN;
  int* eids   = ip; ip += ET;
  int* srcs   = ip;

  const int TB = 256;
  k_detect<<<1, 256, 0, stream>>>((const int*)ei, flag);
  k_init<<<(NN+TB-1)/TB, TB, 0, stream>>>(m1, z1, as1, ad1, m2, z2, as2, ad2,
                                          deg, bns1, bnq1, bns2, bnq2);
  // CSR build (shared by both layers)
  k_degree<<<(ER+TB-1)/TB, TB, 0, stream>>>(ei, flag, deg);
  k_scan1<<<40, 512, 0, stream>>>(deg, offs, bsum);
  k_scan2<<<1, 64, 0, stream>>>(bsum);
  k_scan3<<<(NN+TB-1)/TB, TB, 0, stream>>>(offs, bsum, cursor);
  k_scatter<<<(ET+TB-1)/TB, TB, 0, stream>>>(ei, flag, cursor, eids, srcs);

  // layer 1
  k_gemm1<<<NN/8, 256, 0, stream>>>(x, W1, hx1);
  k_att<C1V><<<NN, HH*C1V, 0, stream>>>(hx1, att_s1, att_d1, as1, ad1);
  k_edge_a<<<(ET+TB-1)/TB, TB, 0, stream>>>(ei, flag, as1, ad1, ev, m1);
  k_edge_b<<<(ET+TB-1)/TB, TB, 0, stream>>>(ei, flag, m1, ev, z1);
  k_agg<C1V><<<NN, HH*C1V, 0, stream>>>(offs, eids, srcs, ev, z1, hx1, bias1, out1);
  k_bnstats<D1><<<200, D1, 0, stream>>>(out1, bns1, bnq1);
  k_bnapply<D1><<<(NN*D1)/TB, TB, 0, stream>>>(out1, bns1, bnq1, gamma1, beta1, h1);

  // layer 2
  k_gemm2<<<NN/16, 256, 0, stream>>>(h1, W2, hx2);
  k_att<C2V><<<NN, HH*C2V, 0, stream>>>(hx2, att_s2, att_d2, as2, ad2);
  k_edge_a<<<(ET+TB-1)/TB, TB, 0, stream>>>(ei, flag, as2, ad2, ev, m2);
  k_edge_b<<<(ET+TB-1)/TB, TB, 0, stream>>>(ei, flag, m2, ev, z2);
  k_agg<C2V><<<NN, HH*C2V, 0, stream>>>(offs, eids, srcs, ev, z2, hx2, bias2, out2);
  k_bnstats<D2><<<200, D2, 0, stream>>>(out2, bns2, bnq2);
  k_bnapply<D2><<<(NN*D2)/TB, TB, 0, stream>>>(out2, bns2, bnq2, gamma2, beta2, (float*)d_out);
}

// Round 2
// 380.168 us; speedup vs baseline: 2.0142x; 2.0142x over previous
//
#include <hip/hip_runtime.h>
#include <hip/hip_bf16.h>
#include <math.h>

#define NN 20000      // nodes
#define ER 640000     // raw edges
#define ET 660000     // edges incl. self loops
#define HH 2          // heads
#define C1V 64
#define D1 128        // HH*C1V
#define C2V 128
#define D2 256        // HH*C2V
#define EPSV 1e-5f
#define SLOPE 0.2f

// ---------- helpers ----------

__device__ __forceinline__ void edge_sd(const void* ei, int is64, int i, int& s, int& d) {
  if (is64) {
    const long long* p = (const long long*)ei;
    s = (int)p[i]; d = (int)p[ER + i];
  } else {
    const int* p = (const int*)ei;
    s = p[i]; d = p[ER + i];
  }
  s = (s < 0) ? 0 : (s >= NN ? NN - 1 : s);   // crash guard only
  d = (d < 0) ? 0 : (d >= NN ? NN - 1 : d);
}

__device__ __forceinline__ float bf16_lo(unsigned int u) {
  return __uint_as_float(u << 16);
}
__device__ __forceinline__ float bf16_hi(unsigned int u) {
  return __uint_as_float(u & 0xffff0000u);
}

// ---------- dtype detect: int64 edge_index has all-zero high int32 words ----------
__global__ void k_detect(const int* ei, int* flag) {
  __shared__ int any;
  if (threadIdx.x == 0) any = 0;
  __syncthreads();
  int t = threadIdx.x;
  int v = ei[2*t+1] | ei[2*(t+256)+1] | ei[2*(t+512)+1] | ei[2*(t+768)+1];
  if (v != 0) atomicOr(&any, 1);
  __syncthreads();
  if (t == 0) *flag = (any == 0) ? 1 : 0;   // 1 => int64
}

// ---------- init (deg=1 for self loop; zero BN accumulators) ----------
__global__ void k_init(int* deg, float* bns1, float* bnq1, float* bns2, float* bnq2) {
  int i = blockIdx.x*blockDim.x + threadIdx.x;
  if (i < NN) deg[i] = 1;
  if (i < D1) { bns1[i] = 0.f; bnq1[i] = 0.f; }
  if (i < D2) { bns2[i] = 0.f; bnq2[i] = 0.f; }
}

// ---------- CSR build ----------
__global__ void k_degree(const void* ei, const int* flag, int* deg) {
  int i = blockIdx.x*blockDim.x + threadIdx.x;
  if (i >= ER) return;
  int s, d; edge_sd(ei, *flag, i, s, d);
  atomicAdd(&deg[d], 1);
}

__global__ void k_scan1(const int* deg, int* offs, int* bsum) {
  __shared__ int sm[512];
  int t = threadIdx.x;
  int i = blockIdx.x*512 + t;
  int v = (i < NN) ? deg[i] : 0;
  sm[t] = v;
  __syncthreads();
  for (int o = 1; o < 512; o <<= 1) {
    int add = (t >= o) ? sm[t-o] : 0;
    __syncthreads();
    sm[t] += add;
    __syncthreads();
  }
  if (i < NN) offs[i] = sm[t] - v;          // block-local exclusive
  if (t == 511) bsum[blockIdx.x] = sm[511];
}

__global__ void k_scan2(int* bsum) {
  __shared__ int sm[64];
  int t = threadIdx.x;
  int v = (t < 40) ? bsum[t] : 0;
  sm[t] = v;
  __syncthreads();
  for (int o = 1; o < 64; o <<= 1) {
    int add = (t >= o) ? sm[t-o] : 0;
    __syncthreads();
    sm[t] += add;
    __syncthreads();
  }
  if (t < 40) bsum[t] = sm[t] - v;          // exclusive over block sums
}

__global__ void k_scan3(int* offs, const int* bsum, int* cursor) {
  int i = blockIdx.x*blockDim.x + threadIdx.x;
  if (i < NN) {
    int o = offs[i] + bsum[i >> 9];
    offs[i] = o;
    cursor[i] = o;
  }
  if (i == 0) offs[NN] = ET;
}

__global__ void k_scatter(const void* ei, const int* flag, int* cursor, int* srcs) {
  int i = blockIdx.x*blockDim.x + threadIdx.x;
  if (i >= ET) return;
  int s, d;
  if (i < ER) edge_sd(ei, *flag, i, s, d); else { s = d = i - ER; }
  int pos = atomicAdd(&cursor[d], 1);
  srcs[pos] = s;
}

// ---------- GEMM1: [NN,64] @ [64,128] -> bf16 hx1b + attention scalars ----------
__global__ __launch_bounds__(256) void k_gemm1(const float* x, const float* W,
                                               const float* att_s, const float* att_d,
                                               __hip_bfloat16* hxb, float* a_s, float* a_d) {
  __shared__ float Wl[64*128];   // 32 KB
  __shared__ float xs[8][64];    // 2 KB
  int t = threadIdx.x;
  const float4* W4 = (const float4*)W;
  float4* Wl4 = (float4*)Wl;
  for (int i = t; i < 64*128/4; i += 256) Wl4[i] = W4[i];
  int r0 = blockIdx.x * 8;
  const float4* x4 = (const float4*)(x + (size_t)r0*64);
  float4* xs4 = (float4*)&xs[0][0];
  if (t < 128) xs4[t] = x4[t];
  __syncthreads();
  int j = t & 127, g = t >> 7;               // g selects rows g*4..g*4+3
  float a0=0.f, a1=0.f, a2=0.f, a3=0.f;
  for (int k = 0; k < 64; k++) {
    float w = Wl[k*128 + j];
    a0 += xs[g*4+0][k]*w;
    a1 += xs[g*4+1][k]*w;
    a2 += xs[g*4+2][k]*w;
    a3 += xs[g*4+3][k]*w;
  }
  int r = r0 + g*4;
  hxb[(size_t)(r+0)*128 + j] = __float2bfloat16(a0);
  hxb[(size_t)(r+1)*128 + j] = __float2bfloat16(a1);
  hxb[(size_t)(r+2)*128 + j] = __float2bfloat16(a2);
  hxb[(size_t)(r+3)*128 + j] = __float2bfloat16(a3);
  // attention epilogue: each wave covers one (g, head); reduce over 64 cols
  float asw = att_s[j];   // flat [2][64] == [128]
  float adw = att_d[j];
  float p0 = a0*asw, p1 = a1*asw, p2 = a2*asw, p3 = a3*asw;
  float q0 = a0*adw, q1 = a1*adw, q2 = a2*adw, q3 = a3*adw;
  #pragma unroll
  for (int o = 32; o; o >>= 1) {
    p0 += __shfl_down(p0, o); p1 += __shfl_down(p1, o);
    p2 += __shfl_down(p2, o); p3 += __shfl_down(p3, o);
    q0 += __shfl_down(q0, o); q1 += __shfl_down(q1, o);
    q2 += __shfl_down(q2, o); q3 += __shfl_down(q3, o);
  }
  if ((t & 63) == 0) {
    int h = j >> 6;
    a_s[(r+0)*HH + h] = p0; a_s[(r+1)*HH + h] = p1;
    a_s[(r+2)*HH + h] = p2; a_s[(r+3)*HH + h] = p3;
    a_d[(r+0)*HH + h] = q0; a_d[(r+1)*HH + h] = q1;
    a_d[(r+2)*HH + h] = q2; a_d[(r+3)*HH + h] = q3;
  }
}

// ---------- GEMM2: [NN,128] @ [128,256] -> bf16 hx2b + attention scalars ----------
__global__ __launch_bounds__(256) void k_gemm2(const float* h1, const float* W,
                                               const float* att_s, const float* att_d,
                                               __hip_bfloat16* hxb, float* a_s, float* a_d) {
  __shared__ float Wl[32*256];   // 32 KB per k-chunk
  __shared__ float xs[16][128];  // 8 KB
  __shared__ float reds[4][16], redd[4][16];
  int t = threadIdx.x;
  int r0 = blockIdx.x * 16;
  const float4* x4 = (const float4*)(h1 + (size_t)r0*128);
  float4* xs4 = (float4*)&xs[0][0];
  for (int i = t; i < 16*128/4; i += 256) xs4[i] = x4[i];
  float acc[16];
  #pragma unroll
  for (int r = 0; r < 16; r++) acc[r] = 0.f;
  const float4* W4 = (const float4*)W;
  float4* Wl4 = (float4*)Wl;
  for (int kc = 0; kc < 4; kc++) {
    __syncthreads();
    for (int i = t; i < 32*256/4; i += 256) Wl4[i] = W4[kc*(32*256/4) + i];
    __syncthreads();
    for (int k = 0; k < 32; k++) {
      float w = Wl[k*256 + t];
      int kk = kc*32 + k;
      #pragma unroll
      for (int r = 0; r < 16; r++) acc[r] += xs[r][kk]*w;
    }
  }
  #pragma unroll
  for (int r = 0; r < 16; r++)
    hxb[(size_t)(r0+r)*256 + t] = __float2bfloat16(acc[r]);
  // attention epilogue: head h = t>>7; waves {0,1}->h0, {2,3}->h1
  float asw = att_s[t];   // flat [2][128] == [256]
  float adw = att_d[t];
  int w = t >> 6;
  #pragma unroll
  for (int r = 0; r < 16; r++) {
    float ps = acc[r]*asw, pd = acc[r]*adw;
    #pragma unroll
    for (int o = 32; o; o >>= 1) { ps += __shfl_down(ps, o); pd += __shfl_down(pd, o); }
    if ((t & 63) == 0) { reds[w][r] = ps; redd[w][r] = pd; }
  }
  __syncthreads();
  if (t < 16) {
    a_s[(r0+t)*HH + 0] = reds[0][t] + reds[1][t];
    a_s[(r0+t)*HH + 1] = reds[2][t] + reds[3][t];
    a_d[(r0+t)*HH + 0] = redd[0][t] + redd[1][t];
    a_d[(r0+t)*HH + 1] = redd[2][t] + redd[3][t];
  }
}

// ---------- fused softmax + aggregation ----------
// alpha = exp(e)/sum(exp(e)) (shift-invariant; |e| <~ 10, safe in fp32).
// One block per node; thread t covers columns 2t, 2t+1 (one uint = 2 bf16).
// D = HH*C columns; blockDim = D/2; head h = t / (C/2).
template<int D>
__global__ void k_agg(const int* offs, const int* srcs,
                      const float* a_s, const float* a_d,
                      const unsigned int* hxb_u,   // bf16 hx, 2 per uint
                      const float* bias, float* out) {
  const int TPB = D/2;
  int n = blockIdx.x;
  int t = threadIdx.x;
  int h = t / (D/4);             // D/4 = C/2 threads per head
  float adn = a_d[n*HH + h];
  int beg = offs[n], end = offs[n+1];
  float acc0 = 0.f, acc1 = 0.f, zacc = 0.f;
  int j = beg;
  for (; j + 3 < end; j += 4) {
    int s0 = srcs[j], s1 = srcs[j+1], s2 = srcs[j+2], s3 = srcs[j+3];
    float e0 = a_s[s0*HH + h] + adn;
    float e1 = a_s[s1*HH + h] + adn;
    float e2 = a_s[s2*HH + h] + adn;
    float e3 = a_s[s3*HH + h] + adn;
    e0 = (e0 > 0.f) ? e0 : SLOPE*e0;  e1 = (e1 > 0.f) ? e1 : SLOPE*e1;
    e2 = (e2 > 0.f) ? e2 : SLOPE*e2;  e3 = (e3 > 0.f) ? e3 : SLOPE*e3;
    float p0 = expf(e0), p1 = expf(e1), p2 = expf(e2), p3 = expf(e3);
    unsigned int u0 = hxb_u[(size_t)s0*TPB + t];
    unsigned int u1 = hxb_u[(size_t)s1*TPB + t];
    unsigned int u2 = hxb_u[(size_t)s2*TPB + t];
    unsigned int u3 = hxb_u[(size_t)s3*TPB + t];
    acc0 += p0*bf16_lo(u0) + p1*bf16_lo(u1) + p2*bf16_lo(u2) + p3*bf16_lo(u3);
    acc1 += p0*bf16_hi(u0) + p1*bf16_hi(u1) + p2*bf16_hi(u2) + p3*bf16_hi(u3);
    zacc += p0 + p1 + p2 + p3;
  }
  for (; j < end; j++) {
    int s = srcs[j];
    float e = a_s[s*HH + h] + adn;
    e = (e > 0.f) ? e : SLOPE*e;
    float p = expf(e);
    unsigned int u = hxb_u[(size_t)s*TPB + t];
    acc0 += p*bf16_lo(u);
    acc1 += p*bf16_hi(u);
    zacc += p;
  }
  float inv = 1.f / zacc;
  float2 o;
  o.x = acc0*inv + bias[2*t];
  o.y = acc1*inv + bias[2*t+1];
  ((float2*)(out + (size_t)n*D))[t] = o;
}

// ---------- batchnorm stats ----------
template<int D>
__global__ void k_bnstats(const float* x, float* bnsum, float* bnsq) {
  const int ROWS = 100;          // grid = 200 blocks, block = D threads
  int c = threadIdx.x;
  int r0 = blockIdx.x * ROWS;
  float s = 0.f, s2 = 0.f;
  for (int r = 0; r < ROWS; r++) {
    float v = x[(size_t)(r0 + r)*D + c];
    s += v; s2 += v*v;
  }
  atomicAdd(&bnsum[c], s);
  atomicAdd(&bnsq[c], s2);
}

// ---------- batchnorm apply + ReLU ----------
template<int D>
__global__ void k_bnapply(const float* x, const float* bnsum, const float* bnsq,
                          const float* gamma, const float* beta, float* out) {
  int i = blockIdx.x*blockDim.x + threadIdx.x;
  if (i >= NN*D) return;
  int c = i & (D-1);
  float mean = bnsum[c] * (1.f/NN);
  float var  = bnsq[c] * (1.f/NN) - mean*mean;
  float v = (x[i] - mean) * rsqrtf(var + EPSV) * gamma[c] + beta[c];
  out[i] = v > 0.f ? v : 0.f;
}

// ---------- launcher ----------
extern "C" void kernel_launch(void* const* d_in, const int* in_sizes, int n_in,
                              void* d_out, int out_size, void* d_ws, size_t ws_size,
                              hipStream_t stream) {
  const float* x      = (const float*)d_in[0];
  const void*  ei     = d_in[1];
  const float* W1     = (const float*)d_in[2];
  const float* att_s1 = (const float*)d_in[3];
  const float* att_d1 = (const float*)d_in[4];
  const float* bias1  = (const float*)d_in[5];
  const float* gamma1 = (const float*)d_in[6];
  const float* beta1  = (const float*)d_in[7];
  const float* W2     = (const float*)d_in[8];
  const float* att_s2 = (const float*)d_in[9];
  const float* att_d2 = (const float*)d_in[10];
  const float* bias2  = (const float*)d_in[11];
  const float* gamma2 = (const float*)d_in[12];
  const float* beta2  = (const float*)d_in[13];

  // workspace layout
  char* p = (char*)d_ws;
  __hip_bfloat16* hx1b = (__hip_bfloat16*)p; p += (size_t)NN*D1*2;   // 5.12 MB
  __hip_bfloat16* hx2b = (__hip_bfloat16*)p; p += (size_t)NN*D2*2;   // 10.24 MB
  float* out1 = (float*)p; p += (size_t)NN*D1*4;                     // 10.24 MB
  float* h1   = (float*)p; p += (size_t)NN*D1*4;                     // 10.24 MB
  float* out2 = (float*)p; p += (size_t)NN*D2*4;                     // 20.48 MB
  float* as1  = (float*)p; p += NN*HH*4;
  float* ad1  = (float*)p; p += NN*HH*4;
  float* as2  = (float*)p; p += NN*HH*4;
  float* ad2  = (float*)p; p += NN*HH*4;
  float* bns1 = (float*)p; p += D1*4;
  float* bnq1 = (float*)p; p += D1*4;
  float* bns2 = (float*)p; p += D2*4;
  float* bnq2 = (float*)p; p += D2*4;
  int* flag   = (int*)p; p += 16*4;
  int* deg    = (int*)p; p += NN*4;
  int* offs   = (int*)p; p += (NN+1)*4;
  int* bsum   = (int*)p; p += 64*4;
  int* cursor = (int*)p; p += NN*4;
  int* srcs   = (int*)p; p += (size_t)ET*4;

  const int TB = 256;
  k_detect<<<1, 256, 0, stream>>>((const int*)ei, flag);
  k_init<<<(NN+TB-1)/TB, TB, 0, stream>>>(deg, bns1, bnq1, bns2, bnq2);
  // CSR build (shared by both layers)
  k_degree<<<(ER+TB-1)/TB, TB, 0, stream>>>(ei, flag, deg);
  k_scan1<<<40, 512, 0, stream>>>(deg, offs, bsum);
  k_scan2<<<1, 64, 0, stream>>>(bsum);
  k_scan3<<<(NN+TB-1)/TB, TB, 0, stream>>>(offs, bsum, cursor);
  k_scatter<<<(ET+TB-1)/TB, TB, 0, stream>>>(ei, flag, cursor, srcs);

  // layer 1
  k_gemm1<<<NN/8, 256, 0, stream>>>(x, W1, att_s1, att_d1, hx1b, as1, ad1);
  k_agg<D1><<<NN, D1/2, 0, stream>>>(offs, srcs, as1, ad1,
                                     (const unsigned int*)hx1b, bias1, out1);
  k_bnstats<D1><<<200, D1, 0, stream>>>(out1, bns1, bnq1);
  k_bnapply<D1><<<(NN*D1)/TB, TB, 0, stream>>>(out1, bns1, bnq1, gamma1, beta1, h1);

  // layer 2
  k_gemm2<<<NN/16, 256, 0, stream>>>(h1, W2, att_s2, att_d2, hx2b, as2, ad2);
  k_agg<D2><<<NN, D2/2, 0, stream>>>(offs, srcs, as2, ad2,
                                     (const unsigned int*)hx2b, bias2, out2);
  k_bnstats<D2><<<200, D2, 0, stream>>>(out2, bns2, bnq2);
  k_bnapply<D2><<<(NN*D2)/TB, TB, 0, stream>>>(out2, bns2, bnq2, gamma2, beta2, (float*)d_out);
}

// Round 4
// 337.647 us; speedup vs baseline: 2.2679x; 1.1259x over previous
//
#include <hip/hip_runtime.h>
#include <hip/hip_bf16.h>
#include <math.h>

#define NN 20000      // nodes
#define ER 640000     // raw edges
#define ET 660000     // edges incl. self loops
#define HH 2          // heads
#define D1 128        // HH*64
#define D2 256        // HH*128
#define EPSV 1e-5f
#define SLOPE 0.2f

typedef __attribute__((ext_vector_type(8))) short bf16x8;
typedef __attribute__((ext_vector_type(4))) float f32x4;

// ---------- helpers ----------

__device__ __forceinline__ void edge_sd(const void* ei, int is64, int i, int& s, int& d) {
  if (is64) {
    const long long* p = (const long long*)ei;
    s = (int)p[i]; d = (int)p[ER + i];
  } else {
    const int* p = (const int*)ei;
    s = p[i]; d = p[ER + i];
  }
  s = (s < 0) ? 0 : (s >= NN ? NN - 1 : s);   // crash guard only
  d = (d < 0) ? 0 : (d >= NN ? NN - 1 : d);
}

__device__ __forceinline__ float bf16_lo(unsigned int u) { return __uint_as_float(u << 16); }
__device__ __forceinline__ float bf16_hi(unsigned int u) { return __uint_as_float(u & 0xffff0000u); }

// ---------- dtype detect ----------
__global__ void k_detect(const int* ei, int* flag) {
  __shared__ int any;
  if (threadIdx.x == 0) any = 0;
  __syncthreads();
  int t = threadIdx.x;
  int v = ei[2*t+1] | ei[2*(t+256)+1] | ei[2*(t+512)+1] | ei[2*(t+768)+1];
  if (v != 0) atomicOr(&any, 1);
  __syncthreads();
  if (t == 0) *flag = (any == 0) ? 1 : 0;   // 1 => int64
}

// ---------- init ----------
__global__ void k_init(int* deg, float* bns1, float* bnq1, float* bns2, float* bnq2) {
  int i = blockIdx.x*blockDim.x + threadIdx.x;
  if (i < NN) deg[i] = 1;
  if (i < D1) { bns1[i] = 0.f; bnq1[i] = 0.f; }
  if (i < D2) { bns2[i] = 0.f; bnq2[i] = 0.f; }
}

// ---------- CSR build ----------
__global__ void k_degree(const void* ei, const int* flag, int* deg) {
  int i = blockIdx.x*blockDim.x + threadIdx.x;
  if (i >= ER) return;
  int s, d; edge_sd(ei, *flag, i, s, d);
  atomicAdd(&deg[d], 1);
}

__global__ void k_scan1(const int* deg, int* offs, int* bsum) {
  __shared__ int sm[512];
  int t = threadIdx.x;
  int i = blockIdx.x*512 + t;
  int v = (i < NN) ? deg[i] : 0;
  sm[t] = v;
  __syncthreads();
  for (int o = 1; o < 512; o <<= 1) {
    int add = (t >= o) ? sm[t-o] : 0;
    __syncthreads();
    sm[t] += add;
    __syncthreads();
  }
  if (i < NN) offs[i] = sm[t] - v;
  if (t == 511) bsum[blockIdx.x] = sm[511];
}

__global__ void k_scan2(int* bsum) {
  __shared__ int sm[64];
  int t = threadIdx.x;
  int v = (t < 40) ? bsum[t] : 0;
  sm[t] = v;
  __syncthreads();
  for (int o = 1; o < 64; o <<= 1) {
    int add = (t >= o) ? sm[t-o] : 0;
    __syncthreads();
    sm[t] += add;
    __syncthreads();
  }
  if (t < 40) bsum[t] = sm[t] - v;
}

__global__ void k_scan3(int* offs, const int* bsum, int* cursor) {
  int i = blockIdx.x*blockDim.x + threadIdx.x;
  if (i < NN) {
    int o = offs[i] + bsum[i >> 9];
    offs[i] = o;
    cursor[i] = o;
  }
  if (i == 0) offs[NN] = ET;
}

__global__ void k_scatter(const void* ei, const int* flag, int* cursor, int* srcs) {
  int i = blockIdx.x*blockDim.x + threadIdx.x;
  if (i >= ET) return;
  int s, d;
  if (i < ER) edge_sd(ei, *flag, i, s, d); else { s = d = i - ER; }
  int pos = atomicAdd(&cursor[d], 1);
  srcs[pos] = s;
}

// ---------- weight prep: transpose+convert to bf16 ----------
// W1t[n][k]: [128][64]; W2c[kc][n][kk]: [4][256][32] (k = kc*32+kk)
__global__ void k_prep_w(const float* W1, const float* W2,
                         __hip_bfloat16* W1t, __hip_bfloat16* W2c) {
  int i = blockIdx.x*blockDim.x + threadIdx.x;
  if (i < 8192) {
    int n = i >> 6, k = i & 63;
    W1t[i] = __float2bfloat16(W1[k*128 + n]);
  } else {
    int i2 = i - 8192;                    // < 32768
    int kc = i2 >> 13, n = (i2 >> 5) & 255, kk = i2 & 31;
    W2c[i2] = __float2bfloat16(W2[(kc*32 + kk)*256 + n]);
  }
}

// ---------- attention-vector prep: ws/wd = W @ att  ----------
// wsd1 flat [4][64]: {ws h0, ws h1, wd h0, wd h1}; wsd2 flat [4][128]
__global__ void k_prep_att(const float* W1, const float* as1, const float* ad1,
                           const float* W2, const float* as2, const float* ad2,
                           float* wsd1, float* wsd2) {
  int t = threadIdx.x;
  {
    int r = t >> 6, k = t & 63, h = r & 1;
    const float* att = (r < 2) ? as1 : ad1;
    float s = 0.f;
    for (int c = 0; c < 64; c++) s += W1[k*128 + h*64 + c] * att[h*64 + c];
    wsd1[t] = s;
  }
  for (int i = t; i < 512; i += 256) {
    int r = i >> 7, k = i & 127, h = r & 1;
    const float* att = (r < 2) ? as2 : ad2;
    float s = 0.f;
    for (int c = 0; c < 128; c++) s += W2[k*256 + h*128 + c] * att[h*128 + c];
    wsd2[i] = s;
  }
}

// ---------- x -> bf16 cast + layer-1 attention scalars (exact fp32 GEMV) ----------
__global__ __launch_bounds__(256) void k_xcast(const float* x, const float* wsd1,
                                               __hip_bfloat16* xb, float* a_s, float* a_d) {
  int n = blockIdx.x*4 + (threadIdx.x >> 6);
  int lane = threadIdx.x & 63;
  float v = x[(size_t)n*64 + lane];
  xb[(size_t)n*64 + lane] = __float2bfloat16(v);
  float p0 = v*wsd1[lane], p1 = v*wsd1[64+lane];
  float p2 = v*wsd1[128+lane], p3 = v*wsd1[192+lane];
  #pragma unroll
  for (int o = 32; o; o >>= 1) {
    p0 += __shfl_down(p0, o); p1 += __shfl_down(p1, o);
    p2 += __shfl_down(p2, o); p3 += __shfl_down(p3, o);
  }
  if (lane == 0) {
    a_s[n*2] = p0; a_s[n*2+1] = p1;
    a_d[n*2] = p2; a_d[n*2+1] = p3;
  }
}

// ---------- MFMA GEMM1: xb[20000x64] @ W1t^T -> hx1b[20000x128] bf16 ----------
__global__ __launch_bounds__(256) void k_gemm1(const __hip_bfloat16* xb,
                                               const __hip_bfloat16* W1t,
                                               __hip_bfloat16* hxb) {
  __shared__ __hip_bfloat16 As[64][72];    // row stride 144 B (16B-aligned)
  __shared__ __hip_bfloat16 Bs[128][72];
  int t = threadIdx.x;
  int m0 = blockIdx.x * 64;
  // As: 64 rows x 64 bf16 = 8 uint4/row -> 512 uint4
  for (int i = t; i < 512; i += 256) {
    int r = i >> 3, s = i & 7;
    int gr = m0 + r; if (gr >= NN) gr = NN - 1;
    *(uint4*)&As[r][s*8] = ((const uint4*)(xb + (size_t)gr*64))[s];
  }
  // Bs: 128 rows x 64 bf16 = 8 uint4/row -> 1024 uint4
  for (int i = t; i < 1024; i += 256) {
    int r = i >> 3, s = i & 7;
    *(uint4*)&Bs[r][s*8] = ((const uint4*)(W1t + (size_t)r*64))[s];
  }
  __syncthreads();
  int w = t >> 6, lane = t & 63;
  int lm = lane & 15, q = lane >> 4;
  f32x4 acc[4][2];
  #pragma unroll
  for (int rt = 0; rt < 4; rt++)
    #pragma unroll
    for (int ct = 0; ct < 2; ct++) acc[rt][ct] = (f32x4){0.f,0.f,0.f,0.f};
  #pragma unroll
  for (int kc = 0; kc < 2; kc++) {
    bf16x8 b[2];
    #pragma unroll
    for (int ct = 0; ct < 2; ct++)
      b[ct] = *(const bf16x8*)&Bs[w*32 + ct*16 + lm][kc*32 + q*8];
    #pragma unroll
    for (int rt = 0; rt < 4; rt++) {
      bf16x8 a = *(const bf16x8*)&As[rt*16 + lm][kc*32 + q*8];
      acc[rt][0] = __builtin_amdgcn_mfma_f32_16x16x32_bf16(a, b[0], acc[rt][0], 0, 0, 0);
      acc[rt][1] = __builtin_amdgcn_mfma_f32_16x16x32_bf16(a, b[1], acc[rt][1], 0, 0, 0);
    }
  }
  #pragma unroll
  for (int rt = 0; rt < 4; rt++)
    #pragma unroll
    for (int ct = 0; ct < 2; ct++)
      #pragma unroll
      for (int rg = 0; rg < 4; rg++) {
        int row = m0 + rt*16 + q*4 + rg;
        int col = w*32 + ct*16 + lm;
        if (row < NN) hxb[(size_t)row*128 + col] = __float2bfloat16(acc[rt][ct][rg]);
      }
}

// ---------- MFMA GEMM2: h1b[20000x128] @ W2 -> hx2b[20000x256] bf16 ----------
__global__ __launch_bounds__(256) void k_gemm2(const __hip_bfloat16* h1b,
                                               const __hip_bfloat16* W2c,
                                               __hip_bfloat16* hxb) {
  __shared__ __hip_bfloat16 As[64][136];   // row stride 272 B (16B-aligned)
  __shared__ __hip_bfloat16 Bs[256][40];   // row stride 80 B (16B-aligned)
  int t = threadIdx.x;
  int m0 = blockIdx.x * 64;
  // As: 64 rows x 128 bf16 = 16 uint4/row? no: 128 bf16 = 256 B = 16 uint4... rows*16=1024
  for (int i = t; i < 1024; i += 256) {
    int r = i >> 4, s = i & 15;
    int gr = m0 + r; if (gr >= NN) gr = NN - 1;
    *(uint4*)&As[r][s*8] = ((const uint4*)(h1b + (size_t)gr*128))[s];
  }
  int w = t >> 6, lane = t & 63;
  int lm = lane & 15, q = lane >> 4;
  f32x4 acc[4][4];
  #pragma unroll
  for (int rt = 0; rt < 4; rt++)
    #pragma unroll
    for (int ct = 0; ct < 4; ct++) acc[rt][ct] = (f32x4){0.f,0.f,0.f,0.f};
  for (int kc = 0; kc < 4; kc++) {
    __syncthreads();
    // Bs: 256 rows x 32 bf16 = 4 uint4/row -> 1024 uint4
    for (int i = t; i < 1024; i += 256) {
      int r = i >> 2, s = i & 3;
      *(uint4*)&Bs[r][s*8] = ((const uint4*)(W2c + ((size_t)kc*256 + r)*32))[s];
    }
    __syncthreads();
    bf16x8 b[4];
    #pragma unroll
    for (int ct = 0; ct < 4; ct++)
      b[ct] = *(const bf16x8*)&Bs[w*64 + ct*16 + lm][q*8];
    #pragma unroll
    for (int rt = 0; rt < 4; rt++) {
      bf16x8 a = *(const bf16x8*)&As[rt*16 + lm][kc*32 + q*8];
      #pragma unroll
      for (int ct = 0; ct < 4; ct++)
        acc[rt][ct] = __builtin_amdgcn_mfma_f32_16x16x32_bf16(a, b[ct], acc[rt][ct], 0, 0, 0);
    }
  }
  #pragma unroll
  for (int rt = 0; rt < 4; rt++)
    #pragma unroll
    for (int ct = 0; ct < 4; ct++)
      #pragma unroll
      for (int rg = 0; rg < 4; rg++) {
        int row = m0 + rt*16 + q*4 + rg;
        int col = w*64 + ct*16 + lm;
        if (row < NN) hxb[(size_t)row*256 + col] = __float2bfloat16(acc[rt][ct][rg]);
      }
}

// ---------- fused softmax + aggregation ----------
template<int D>
__global__ void k_agg(const int* offs, const int* srcs,
                      const float* a_s, const float* a_d,
                      const unsigned int* hxb_u,
                      const float* bias, float* out) {
  const int TPB = D/2;
  int n = blockIdx.x;
  int t = threadIdx.x;
  int h = t / (D/4);
  float adn = a_d[n*HH + h];
  int beg = offs[n], end = offs[n+1];
  float acc0 = 0.f, acc1 = 0.f, zacc = 0.f;
  int j = beg;
  for (; j + 3 < end; j += 4) {
    int s0 = srcs[j], s1 = srcs[j+1], s2 = srcs[j+2], s3 = srcs[j+3];
    float e0 = a_s[s0*HH + h] + adn;
    float e1 = a_s[s1*HH + h] + adn;
    float e2 = a_s[s2*HH + h] + adn;
    float e3 = a_s[s3*HH + h] + adn;
    e0 = (e0 > 0.f) ? e0 : SLOPE*e0;  e1 = (e1 > 0.f) ? e1 : SLOPE*e1;
    e2 = (e2 > 0.f) ? e2 : SLOPE*e2;  e3 = (e3 > 0.f) ? e3 : SLOPE*e3;
    float p0 = expf(e0), p1 = expf(e1), p2 = expf(e2), p3 = expf(e3);
    unsigned int u0 = hxb_u[(size_t)s0*TPB + t];
    unsigned int u1 = hxb_u[(size_t)s1*TPB + t];
    unsigned int u2 = hxb_u[(size_t)s2*TPB + t];
    unsigned int u3 = hxb_u[(size_t)s3*TPB + t];
    acc0 += p0*bf16_lo(u0) + p1*bf16_lo(u1) + p2*bf16_lo(u2) + p3*bf16_lo(u3);
    acc1 += p0*bf16_hi(u0) + p1*bf16_hi(u1) + p2*bf16_hi(u2) + p3*bf16_hi(u3);
    zacc += p0 + p1 + p2 + p3;
  }
  for (; j < end; j++) {
    int s = srcs[j];
    float e = a_s[s*HH + h] + adn;
    e = (e > 0.f) ? e : SLOPE*e;
    float p = expf(e);
    unsigned int u = hxb_u[(size_t)s*TPB + t];
    acc0 += p*bf16_lo(u);
    acc1 += p*bf16_hi(u);
    zacc += p;
  }
  float inv = 1.f / zacc;
  float2 o;
  o.x = acc0*inv + bias[2*t];
  o.y = acc1*inv + bias[2*t+1];
  ((float2*)(out + (size_t)n*D))[t] = o;
}

// ---------- batchnorm stats ----------
template<int D>
__global__ void k_bnstats(const float* x, float* bnsum, float* bnsq) {
  const int ROWS = 100;
  int c = threadIdx.x;
  int r0 = blockIdx.x * ROWS;
  float s = 0.f, s2 = 0.f;
  for (int r = 0; r < ROWS; r++) {
    float v = x[(size_t)(r0 + r)*D + c];
    s += v; s2 += v*v;
  }
  atomicAdd(&bnsum[c], s);
  atomicAdd(&bnsq[c], s2);
}

// ---------- BN1 apply + ReLU -> bf16 h1 + layer-2 attention scalars ----------
__global__ __launch_bounds__(256) void k_bnapply1(const float* x, const float* bnsum,
                                                  const float* bnsq, const float* gamma,
                                                  const float* beta, const float* wsd2,
                                                  __hip_bfloat16* h1b, float* a_s, float* a_d) {
  int n = blockIdx.x*4 + (threadIdx.x >> 6);
  int lane = threadIdx.x & 63;
  int c0 = 2*lane, c1 = 2*lane + 1;
  float2 v = ((const float2*)(x + (size_t)n*128))[lane];
  float mean0 = bnsum[c0]*(1.f/NN), mean1 = bnsum[c1]*(1.f/NN);
  float var0 = bnsq[c0]*(1.f/NN) - mean0*mean0;
  float var1 = bnsq[c1]*(1.f/NN) - mean1*mean1;
  float h0 = (v.x - mean0)*rsqrtf(var0 + EPSV)*gamma[c0] + beta[c0];
  float h1 = (v.y - mean1)*rsqrtf(var1 + EPSV)*gamma[c1] + beta[c1];
  h0 = h0 > 0.f ? h0 : 0.f;
  h1 = h1 > 0.f ? h1 : 0.f;
  __hip_bfloat162 hb;
  hb.x = __float2bfloat16(h0); hb.y = __float2bfloat16(h1);
  ((__hip_bfloat162*)(h1b + (size_t)n*128))[lane] = hb;
  float p0 = h0*wsd2[c0]       + h1*wsd2[c1];         // a_s head 0
  float p1 = h0*wsd2[128+c0]   + h1*wsd2[128+c1];     // a_s head 1
  float p2 = h0*wsd2[256+c0]   + h1*wsd2[256+c1];     // a_d head 0
  float p3 = h0*wsd2[384+c0]   + h1*wsd2[384+c1];     // a_d head 1
  #pragma unroll
  for (int o = 32; o; o >>= 1) {
    p0 += __shfl_down(p0, o); p1 += __shfl_down(p1, o);
    p2 += __shfl_down(p2, o); p3 += __shfl_down(p3, o);
  }
  if (lane == 0) {
    a_s[n*2] = p0; a_s[n*2+1] = p1;
    a_d[n*2] = p2; a_d[n*2+1] = p3;
  }
}

// ---------- BN2 apply + ReLU -> fp32 out ----------
template<int D>
__global__ void k_bnapply(const float* x, const float* bnsum, const float* bnsq,
                          const float* gamma, const float* beta, float* out) {
  int i = blockIdx.x*blockDim.x + threadIdx.x;
  if (i >= NN*D) return;
  int c = i & (D-1);
  float mean = bnsum[c] * (1.f/NN);
  float var  = bnsq[c] * (1.f/NN) - mean*mean;
  float v = (x[i] - mean) * rsqrtf(var + EPSV) * gamma[c] + beta[c];
  out[i] = v > 0.f ? v : 0.f;
}

// ---------- launcher ----------
extern "C" void kernel_launch(void* const* d_in, const int* in_sizes, int n_in,
                              void* d_out, int out_size, void* d_ws, size_t ws_size,
                              hipStream_t stream) {
  const float* x      = (const float*)d_in[0];
  const void*  ei     = d_in[1];
  const float* W1     = (const float*)d_in[2];
  const float* att_s1 = (const float*)d_in[3];
  const float* att_d1 = (const float*)d_in[4];
  const float* bias1  = (const float*)d_in[5];
  const float* gamma1 = (const float*)d_in[6];
  const float* beta1  = (const float*)d_in[7];
  const float* W2     = (const float*)d_in[8];
  const float* att_s2 = (const float*)d_in[9];
  const float* att_d2 = (const float*)d_in[10];
  const float* bias2  = (const float*)d_in[11];
  const float* gamma2 = (const float*)d_in[12];
  const float* beta2  = (const float*)d_in[13];

  char* p = (char*)d_ws;
  __hip_bfloat16* xb   = (__hip_bfloat16*)p; p += (size_t)NN*64*2;
  __hip_bfloat16* hx1b = (__hip_bfloat16*)p; p += (size_t)NN*D1*2;
  __hip_bfloat16* h1b  = (__hip_bfloat16*)p; p += (size_t)NN*D1*2;
  __hip_bfloat16* hx2b = (__hip_bfloat16*)p; p += (size_t)NN*D2*2;
  __hip_bfloat16* W1t  = (__hip_bfloat16*)p; p += 8192*2;
  __hip_bfloat16* W2c  = (__hip_bfloat16*)p; p += 32768*2;
  float* out1 = (float*)p; p += (size_t)NN*D1*4;
  float* out2 = (float*)p; p += (size_t)NN*D2*4;
  float* wsd1 = (float*)p; p += 256*4;
  float* wsd2 = (float*)p; p += 512*4;
  float* as1  = (float*)p; p += NN*HH*4;
  float* ad1  = (float*)p; p += NN*HH*4;
  float* as2  = (float*)p; p += NN*HH*4;
  float* ad2  = (float*)p; p += NN*HH*4;
  float* bns1 = (float*)p; p += D1*4;
  float* bnq1 = (float*)p; p += D1*4;
  float* bns2 = (float*)p; p += D2*4;
  float* bnq2 = (float*)p; p += D2*4;
  int* flag   = (int*)p; p += 16*4;
  int* deg    = (int*)p; p += NN*4;
  int* offs   = (int*)p; p += (NN+1)*4;
  int* bsum   = (int*)p; p += 64*4;
  int* cursor = (int*)p; p += NN*4;
  int* srcs   = (int*)p; p += (size_t)ET*4;

  const int TB = 256;
  k_detect<<<1, 256, 0, stream>>>((const int*)ei, flag);
  k_init<<<(NN+TB-1)/TB, TB, 0, stream>>>(deg, bns1, bnq1, bns2, bnq2);
  k_prep_w<<<160, 256, 0, stream>>>(W1, W2, W1t, W2c);
  k_prep_att<<<1, 256, 0, stream>>>(W1, att_s1, att_d1, W2, att_s2, att_d2, wsd1, wsd2);
  k_xcast<<<NN/4, 256, 0, stream>>>(x, wsd1, xb, as1, ad1);
  // CSR build (shared by both layers)
  k_degree<<<(ER+TB-1)/TB, TB, 0, stream>>>(ei, flag, deg);
  k_scan1<<<40, 512, 0, stream>>>(deg, offs, bsum);
  k_scan2<<<1, 64, 0, stream>>>(bsum);
  k_scan3<<<(NN+TB-1)/TB, TB, 0, stream>>>(offs, bsum, cursor);
  k_scatter<<<(ET+TB-1)/TB, TB, 0, stream>>>(ei, flag, cursor, srcs);

  // layer 1
  k_gemm1<<<(NN+63)/64, 256, 0, stream>>>(xb, W1t, hx1b);
  k_agg<D1><<<NN, D1/2, 0, stream>>>(offs, srcs, as1, ad1,
                                     (const unsigned int*)hx1b, bias1, out1);
  k_bnstats<D1><<<200, D1, 0, stream>>>(out1, bns1, bnq1);
  k_bnapply1<<<NN/4, 256, 0, stream>>>(out1, bns1, bnq1, gamma1, beta1, wsd2,
                                       h1b, as2, ad2);

  // layer 2
  k_gemm2<<<(NN+63)/64, 256, 0, stream>>>(h1b, W2c, hx2b);
  k_agg<D2><<<NN, D2/2, 0, stream>>>(offs, srcs, as2, ad2,
                                     (const unsigned int*)hx2b, bias2, out2);
  k_bnstats<D2><<<200, D2, 0, stream>>>(out2, bns2, bnq2);
  k_bnapply<D2><<<(NN*D2)/TB, TB, 0, stream>>>(out2, bns2, bnq2, gamma2, beta2, (float*)d_out);
}

// Round 5
// 318.067 us; speedup vs baseline: 2.4075x; 1.0616x over previous
//
#include <hip/hip_runtime.h>
#include <hip/hip_bf16.h>
#include <math.h>

#define NN 20000      // nodes
#define ER 640000     // raw edges
#define ET 660000     // edges incl. self loops
#define HH 2          // heads
#define D1 128        // HH*64
#define D2 256        // HH*128
#define EPSV 1e-5f
#define SLOPE 0.2f

typedef __attribute__((ext_vector_type(8))) short bf16x8;
typedef __attribute__((ext_vector_type(4))) float f32x4;

// ---------- helpers ----------

// int64 edge_index has all-zero high int32 words; 4 random node-ids all ==0
// has P ~ (1/20000)^4 — negligible. Uniform address -> compiler scalarizes.
__device__ __forceinline__ int detect64(const void* ei) {
  const int* p = (const int*)ei;
  return (p[1] | p[3] | p[5] | p[7]) == 0;
}

__device__ __forceinline__ void edge_sd(const void* ei, int is64, int i, int& s, int& d) {
  if (is64) {
    const long long* p = (const long long*)ei;
    s = (int)p[i]; d = (int)p[ER + i];
  } else {
    const int* p = (const int*)ei;
    s = p[i]; d = p[ER + i];
  }
  s = (s < 0) ? 0 : (s >= NN ? NN - 1 : s);   // crash guard only
  d = (d < 0) ? 0 : (d >= NN ? NN - 1 : d);
}

__device__ __forceinline__ float bf16_lo(unsigned int u) { return __uint_as_float(u << 16); }
__device__ __forceinline__ float bf16_hi(unsigned int u) { return __uint_as_float(u & 0xffff0000u); }

// ---------- zero deg + BN accumulators (contiguous region) ----------
__global__ void k_zero(int* z, int count) {
  int i = blockIdx.x*blockDim.x + threadIdx.x;
  if (i < count) z[i] = 0;
}

// ---------- fused prep: W transpose/cast + attention vectors + degree ----------
// blocks 0..159: prep_w; block 160: prep_att; blocks 161..640: degree histogram
__global__ void k_prep(const void* ei, const float* W1, const float* W2,
                       const float* as1, const float* ad1,
                       const float* as2, const float* ad2,
                       __hip_bfloat16* W1t, __hip_bfloat16* W2c,
                       float* wsd1, float* wsd2, int* deg) {
  int b = blockIdx.x, t = threadIdx.x;
  if (b < 160) {
    int i = b*256 + t;
    if (i < 8192) {             // W1t[n][k]: [128][64]
      int n = i >> 6, k = i & 63;
      W1t[i] = __float2bfloat16(W1[k*128 + n]);
    } else {                    // W2c[kc][n][kk]: [4][256][32]
      int i2 = i - 8192;
      int kc = i2 >> 13, n = (i2 >> 5) & 255, kk = i2 & 31;
      W2c[i2] = __float2bfloat16(W2[(kc*32 + kk)*256 + n]);
    }
  } else if (b == 160) {
    // wsd1 flat [4][64]: {ws h0, ws h1, wd h0, wd h1}; wsd2 flat [4][128]
    {
      int r = t >> 6, k = t & 63, h = r & 1;
      const float* att = (r < 2) ? as1 : ad1;
      float s = 0.f;
      for (int c = 0; c < 64; c++) s += W1[k*128 + h*64 + c] * att[h*64 + c];
      wsd1[t] = s;
    }
    for (int i = t; i < 512; i += 256) {
      int r = i >> 7, k = i & 127, h = r & 1;
      const float* att = (r < 2) ? as2 : ad2;
      float s = 0.f;
      for (int c = 0; c < 128; c++) s += W2[k*256 + h*128 + c] * att[h*128 + c];
      wsd2[i] = s;
    }
  } else {
    int is64 = detect64(ei);
    const int STR = 480*256;
    for (int i = (b - 161)*256 + t; i < ER; i += STR) {
      int s, d; edge_sd(ei, is64, i, s, d);
      atomicAdd(&deg[d], 1);
    }
  }
}

// ---------- single-block scan over 20000 degrees (+1 self loop each) ----------
__global__ __launch_bounds__(1024) void k_scan(const int* deg, int* offs, int* cursor) {
  __shared__ int sm[1024];
  int t = threadIdx.x;
  int base = t*20;               // 1024*20 = 20480 >= NN
  int loc[20]; int s = 0;
  #pragma unroll
  for (int k = 0; k < 20; k++) {
    int idx = base + k;
    int v = (idx < NN) ? (deg[idx] + 1) : 0;   // +1 = self loop
    loc[k] = s; s += v;
  }
  sm[t] = s;
  __syncthreads();
  for (int o = 1; o < 1024; o <<= 1) {
    int add = (t >= o) ? sm[t-o] : 0;
    __syncthreads();
    sm[t] += add;
    __syncthreads();
  }
  int excl = sm[t] - s;
  #pragma unroll
  for (int k = 0; k < 20; k++) {
    int idx = base + k;
    if (idx < NN) { int o = excl + loc[k]; offs[idx] = o; cursor[idx] = o; }
  }
  if (t == 0) offs[NN] = ET;
}

__global__ void k_scatter(const void* ei, int* cursor, int* srcs) {
  int is64 = detect64(ei);
  int i = blockIdx.x*blockDim.x + threadIdx.x;
  if (i >= ET) return;
  int s, d;
  if (i < ER) edge_sd(ei, is64, i, s, d); else { s = d = i - ER; }
  int pos = atomicAdd(&cursor[d], 1);
  srcs[pos] = s;
}

// ---------- x -> bf16 cast + layer-1 attention scalars (exact fp32 GEMV) ----------
__global__ __launch_bounds__(256) void k_xcast(const float* x, const float* wsd1,
                                               __hip_bfloat16* xb, float* a_s, float* a_d) {
  int n = blockIdx.x*4 + (threadIdx.x >> 6);
  int lane = threadIdx.x & 63;
  float v = x[(size_t)n*64 + lane];
  xb[(size_t)n*64 + lane] = __float2bfloat16(v);
  float p0 = v*wsd1[lane], p1 = v*wsd1[64+lane];
  float p2 = v*wsd1[128+lane], p3 = v*wsd1[192+lane];
  #pragma unroll
  for (int o = 32; o; o >>= 1) {
    p0 += __shfl_down(p0, o); p1 += __shfl_down(p1, o);
    p2 += __shfl_down(p2, o); p3 += __shfl_down(p3, o);
  }
  if (lane == 0) {
    a_s[n*2] = p0; a_s[n*2+1] = p1;
    a_d[n*2] = p2; a_d[n*2+1] = p3;
  }
}

// ---------- MFMA GEMM1: xb[20000x64] @ W1t^T -> hx1b[20000x128] bf16 ----------
__global__ __launch_bounds__(256) void k_gemm1(const __hip_bfloat16* xb,
                                               const __hip_bfloat16* W1t,
                                               __hip_bfloat16* hxb) {
  __shared__ __hip_bfloat16 As[64][72];
  __shared__ __hip_bfloat16 Bs[128][72];
  int t = threadIdx.x;
  int m0 = blockIdx.x * 64;
  for (int i = t; i < 512; i += 256) {
    int r = i >> 3, s = i & 7;
    int gr = m0 + r; if (gr >= NN) gr = NN - 1;
    *(uint4*)&As[r][s*8] = ((const uint4*)(xb + (size_t)gr*64))[s];
  }
  for (int i = t; i < 1024; i += 256) {
    int r = i >> 3, s = i & 7;
    *(uint4*)&Bs[r][s*8] = ((const uint4*)(W1t + (size_t)r*64))[s];
  }
  __syncthreads();
  int w = t >> 6, lane = t & 63;
  int lm = lane & 15, q = lane >> 4;
  f32x4 acc[4][2];
  #pragma unroll
  for (int rt = 0; rt < 4; rt++)
    #pragma unroll
    for (int ct = 0; ct < 2; ct++) acc[rt][ct] = (f32x4){0.f,0.f,0.f,0.f};
  #pragma unroll
  for (int kc = 0; kc < 2; kc++) {
    bf16x8 b[2];
    #pragma unroll
    for (int ct = 0; ct < 2; ct++)
      b[ct] = *(const bf16x8*)&Bs[w*32 + ct*16 + lm][kc*32 + q*8];
    #pragma unroll
    for (int rt = 0; rt < 4; rt++) {
      bf16x8 a = *(const bf16x8*)&As[rt*16 + lm][kc*32 + q*8];
      acc[rt][0] = __builtin_amdgcn_mfma_f32_16x16x32_bf16(a, b[0], acc[rt][0], 0, 0, 0);
      acc[rt][1] = __builtin_amdgcn_mfma_f32_16x16x32_bf16(a, b[1], acc[rt][1], 0, 0, 0);
    }
  }
  #pragma unroll
  for (int rt = 0; rt < 4; rt++)
    #pragma unroll
    for (int ct = 0; ct < 2; ct++)
      #pragma unroll
      for (int rg = 0; rg < 4; rg++) {
        int row = m0 + rt*16 + q*4 + rg;
        int col = w*32 + ct*16 + lm;
        if (row < NN) hxb[(size_t)row*128 + col] = __float2bfloat16(acc[rt][ct][rg]);
      }
}

// ---------- MFMA GEMM2: h1b[20000x128] @ W2 -> hx2b[20000x256] bf16 ----------
__global__ __launch_bounds__(256) void k_gemm2(const __hip_bfloat16* h1b,
                                               const __hip_bfloat16* W2c,
                                               __hip_bfloat16* hxb) {
  __shared__ __hip_bfloat16 As[64][136];
  __shared__ __hip_bfloat16 Bs[256][40];
  int t = threadIdx.x;
  int m0 = blockIdx.x * 64;
  for (int i = t; i < 1024; i += 256) {
    int r = i >> 4, s = i & 15;
    int gr = m0 + r; if (gr >= NN) gr = NN - 1;
    *(uint4*)&As[r][s*8] = ((const uint4*)(h1b + (size_t)gr*128))[s];
  }
  int w = t >> 6, lane = t & 63;
  int lm = lane & 15, q = lane >> 4;
  f32x4 acc[4][4];
  #pragma unroll
  for (int rt = 0; rt < 4; rt++)
    #pragma unroll
    for (int ct = 0; ct < 4; ct++) acc[rt][ct] = (f32x4){0.f,0.f,0.f,0.f};
  for (int kc = 0; kc < 4; kc++) {
    __syncthreads();
    for (int i = t; i < 1024; i += 256) {
      int r = i >> 2, s = i & 3;
      *(uint4*)&Bs[r][s*8] = ((const uint4*)(W2c + ((size_t)kc*256 + r)*32))[s];
    }
    __syncthreads();
    bf16x8 b[4];
    #pragma unroll
    for (int ct = 0; ct < 4; ct++)
      b[ct] = *(const bf16x8*)&Bs[w*64 + ct*16 + lm][q*8];
    #pragma unroll
    for (int rt = 0; rt < 4; rt++) {
      bf16x8 a = *(const bf16x8*)&As[rt*16 + lm][kc*32 + q*8];
      #pragma unroll
      for (int ct = 0; ct < 4; ct++)
        acc[rt][ct] = __builtin_amdgcn_mfma_f32_16x16x32_bf16(a, b[ct], acc[rt][ct], 0, 0, 0);
    }
  }
  #pragma unroll
  for (int rt = 0; rt < 4; rt++)
    #pragma unroll
    for (int ct = 0; ct < 4; ct++)
      #pragma unroll
      for (int rg = 0; rg < 4; rg++) {
        int row = m0 + rt*16 + q*4 + rg;
        int col = w*64 + ct*16 + lm;
        if (row < NN) hxb[(size_t)row*256 + col] = __float2bfloat16(acc[rt][ct][rg]);
      }
}

// ---------- fused softmax + aggregation, two-phase ----------
// Phase A: TPB threads each compute (src, p=exp(leaky(e))) for ONE edge of the
// chunk (both heads), store to LDS, accumulate z partials. Phase B: all threads
// sweep the chunk doing the gather+FMA with broadcast LDS reads of (src,p).
// Removes the 128x-replicated expf/a_s-gather chain that made R4 VALU-bound.
template<int D>
__global__ __launch_bounds__(D/2) void k_agg(const int* offs, const int* srcs,
                      const float2* asv, const float2* adv,
                      const unsigned int* hxb_u, const float* bias, float* out) {
  const int TPB = D/2;
  __shared__ alignas(16) float2 sp[2][TPB];   // sp[h][j] = (src-as-bits, p)
  __shared__ float zred[2][2];
  int n = blockIdx.x;
  int t = threadIdx.x;
  int h = t / (TPB/2);
  int w = t >> 6, lane = t & 63;
  float2 ad = adv[n];
  int beg = offs[n], end = offs[n+1];
  float acc0 = 0.f, acc1 = 0.f, z0 = 0.f, z1 = 0.f;
  for (int cb = beg; cb < end; cb += TPB) {
    int len = end - cb; if (len > TPB) len = TPB;
    if (t < len) {
      int s = srcs[cb + t];
      float2 as = asv[s];
      float e0 = as.x + ad.x, e1 = as.y + ad.y;
      e0 = e0 > 0.f ? e0 : SLOPE*e0;
      e1 = e1 > 0.f ? e1 : SLOPE*e1;
      float p0 = __expf(e0), p1 = __expf(e1);
      sp[0][t] = make_float2(__int_as_float(s), p0);
      sp[1][t] = make_float2(__int_as_float(s), p1);
      z0 += p0; z1 += p1;
    }
    __syncthreads();
    int j = 0;
    for (; j + 3 < len; j += 4) {
      float2 v0 = sp[h][j],   v1 = sp[h][j+1];
      float2 v2 = sp[h][j+2], v3 = sp[h][j+3];
      unsigned int u0 = hxb_u[(size_t)__float_as_int(v0.x)*TPB + t];
      unsigned int u1 = hxb_u[(size_t)__float_as_int(v1.x)*TPB + t];
      unsigned int u2 = hxb_u[(size_t)__float_as_int(v2.x)*TPB + t];
      unsigned int u3 = hxb_u[(size_t)__float_as_int(v3.x)*TPB + t];
      acc0 += v0.y*bf16_lo(u0) + v1.y*bf16_lo(u1) + v2.y*bf16_lo(u2) + v3.y*bf16_lo(u3);
      acc1 += v0.y*bf16_hi(u0) + v1.y*bf16_hi(u1) + v2.y*bf16_hi(u2) + v3.y*bf16_hi(u3);
    }
    for (; j < len; j++) {
      float2 v = sp[h][j];
      unsigned int u = hxb_u[(size_t)__float_as_int(v.x)*TPB + t];
      acc0 += v.y*bf16_lo(u);
      acc1 += v.y*bf16_hi(u);
    }
    __syncthreads();
  }
  #pragma unroll
  for (int o = 32; o; o >>= 1) { z0 += __shfl_down(z0, o); z1 += __shfl_down(z1, o); }
  if (lane == 0) { zred[w][0] = z0; zred[w][1] = z1; }
  __syncthreads();
  float zh = zred[0][h];
  if (TPB > 64) zh += zred[1][h];
  float inv = 1.f / zh;
  float2 o2;
  o2.x = acc0*inv + bias[2*t];
  o2.y = acc1*inv + bias[2*t+1];
  ((float2*)(out + (size_t)n*D))[t] = o2;
}

// ---------- batchnorm stats ----------
template<int D>
__global__ void k_bnstats(const float* x, float* bnsum, float* bnsq) {
  const int ROWS = 100;
  int c = threadIdx.x;
  int r0 = blockIdx.x * ROWS;
  float s = 0.f, s2 = 0.f;
  for (int r = 0; r < ROWS; r++) {
    float v = x[(size_t)(r0 + r)*D + c];
    s += v; s2 += v*v;
  }
  atomicAdd(&bnsum[c], s);
  atomicAdd(&bnsq[c], s2);
}

// ---------- BN1 apply + ReLU -> bf16 h1 + layer-2 attention scalars ----------
__global__ __launch_bounds__(256) void k_bnapply1(const float* x, const float* bnsum,
                                                  const float* bnsq, const float* gamma,
                                                  const float* beta, const float* wsd2,
                                                  __hip_bfloat16* h1b, float* a_s, float* a_d) {
  int n = blockIdx.x*4 + (threadIdx.x >> 6);
  int lane = threadIdx.x & 63;
  int c0 = 2*lane, c1 = 2*lane + 1;
  float2 v = ((const float2*)(x + (size_t)n*128))[lane];
  float mean0 = bnsum[c0]*(1.f/NN), mean1 = bnsum[c1]*(1.f/NN);
  float var0 = bnsq[c0]*(1.f/NN) - mean0*mean0;
  float var1 = bnsq[c1]*(1.f/NN) - mean1*mean1;
  float h0 = (v.x - mean0)*rsqrtf(var0 + EPSV)*gamma[c0] + beta[c0];
  float h1 = (v.y - mean1)*rsqrtf(var1 + EPSV)*gamma[c1] + beta[c1];
  h0 = h0 > 0.f ? h0 : 0.f;
  h1 = h1 > 0.f ? h1 : 0.f;
  __hip_bfloat162 hb;
  hb.x = __float2bfloat16(h0); hb.y = __float2bfloat16(h1);
  ((__hip_bfloat162*)(h1b + (size_t)n*128))[lane] = hb;
  float p0 = h0*wsd2[c0]       + h1*wsd2[c1];
  float p1 = h0*wsd2[128+c0]   + h1*wsd2[128+c1];
  float p2 = h0*wsd2[256+c0]   + h1*wsd2[256+c1];
  float p3 = h0*wsd2[384+c0]   + h1*wsd2[384+c1];
  #pragma unroll
  for (int o = 32; o; o >>= 1) {
    p0 += __shfl_down(p0, o); p1 += __shfl_down(p1, o);
    p2 += __shfl_down(p2, o); p3 += __shfl_down(p3, o);
  }
  if (lane == 0) {
    a_s[n*2] = p0; a_s[n*2+1] = p1;
    a_d[n*2] = p2; a_d[n*2+1] = p3;
  }
}

// ---------- BN2 apply + ReLU -> fp32 out ----------
template<int D>
__global__ void k_bnapply(const float* x, const float* bnsum, const float* bnsq,
                          const float* gamma, const float* beta, float* out) {
  int i = blockIdx.x*blockDim.x + threadIdx.x;
  if (i >= NN*D) return;
  int c = i & (D-1);
  float mean = bnsum[c] * (1.f/NN);
  float var  = bnsq[c] * (1.f/NN) - mean*mean;
  float v = (x[i] - mean) * rsqrtf(var + EPSV) * gamma[c] + beta[c];
  out[i] = v > 0.f ? v : 0.f;
}

// ---------- launcher ----------
extern "C" void kernel_launch(void* const* d_in, const int* in_sizes, int n_in,
                              void* d_out, int out_size, void* d_ws, size_t ws_size,
                              hipStream_t stream) {
  const float* x      = (const float*)d_in[0];
  const void*  ei     = d_in[1];
  const float* W1     = (const float*)d_in[2];
  const float* att_s1 = (const float*)d_in[3];
  const float* att_d1 = (const float*)d_in[4];
  const float* bias1  = (const float*)d_in[5];
  const float* gamma1 = (const float*)d_in[6];
  const float* beta1  = (const float*)d_in[7];
  const float* W2     = (const float*)d_in[8];
  const float* att_s2 = (const float*)d_in[9];
  const float* att_d2 = (const float*)d_in[10];
  const float* bias2  = (const float*)d_in[11];
  const float* gamma2 = (const float*)d_in[12];
  const float* beta2  = (const float*)d_in[13];

  char* p = (char*)d_ws;
  __hip_bfloat16* xb   = (__hip_bfloat16*)p; p += (size_t)NN*64*2;
  __hip_bfloat16* hx1b = (__hip_bfloat16*)p; p += (size_t)NN*D1*2;
  __hip_bfloat16* h1b  = (__hip_bfloat16*)p; p += (size_t)NN*D1*2;
  __hip_bfloat16* hx2b = (__hip_bfloat16*)p; p += (size_t)NN*D2*2;
  __hip_bfloat16* W1t  = (__hip_bfloat16*)p; p += 8192*2;
  __hip_bfloat16* W2c  = (__hip_bfloat16*)p; p += 32768*2;
  float* out1 = (float*)p; p += (size_t)NN*D1*4;
  float* out2 = (float*)p; p += (size_t)NN*D2*4;
  float* wsd1 = (float*)p; p += 256*4;
  float* wsd2 = (float*)p; p += 512*4;
  float* as1  = (float*)p; p += NN*HH*4;
  float* ad1  = (float*)p; p += NN*HH*4;
  float* as2  = (float*)p; p += NN*HH*4;
  float* ad2  = (float*)p; p += NN*HH*4;
  // zero region: [deg | bns1 | bnq1 | bns2 | bnq2] contiguous
  int*   deg  = (int*)p;   p += NN*4;
  float* bns1 = (float*)p; p += D1*4;
  float* bnq1 = (float*)p; p += D1*4;
  float* bns2 = (float*)p; p += D2*4;
  float* bnq2 = (float*)p; p += D2*4;
  const int ZCOUNT = NN + 2*D1 + 2*D2;
  int* offs   = (int*)p; p += (NN+1)*4;
  int* cursor = (int*)p; p += NN*4;
  int* srcs   = (int*)p; p += (size_t)ET*4;

  const int TB = 256;
  k_zero<<<(ZCOUNT+TB-1)/TB, TB, 0, stream>>>(deg, ZCOUNT);
  k_prep<<<641, 256, 0, stream>>>(ei, W1, W2, att_s1, att_d1, att_s2, att_d2,
                                  W1t, W2c, wsd1, wsd2, deg);
  k_scan<<<1, 1024, 0, stream>>>(deg, offs, cursor);
  k_scatter<<<(ET+TB-1)/TB, TB, 0, stream>>>(ei, cursor, srcs);
  k_xcast<<<NN/4, 256, 0, stream>>>(x, wsd1, xb, as1, ad1);

  // layer 1
  k_gemm1<<<(NN+63)/64, 256, 0, stream>>>(xb, W1t, hx1b);
  k_agg<D1><<<NN, D1/2, 0, stream>>>(offs, srcs, (const float2*)as1, (const float2*)ad1,
                                     (const unsigned int*)hx1b, bias1, out1);
  k_bnstats<D1><<<200, D1, 0, stream>>>(out1, bns1, bnq1);
  k_bnapply1<<<NN/4, 256, 0, stream>>>(out1, bns1, bnq1, gamma1, beta1, wsd2,
                                       h1b, as2, ad2);

  // layer 2
  k_gemm2<<<(NN+63)/64, 256, 0, stream>>>(h1b, W2c, hx2b);
  k_agg<D2><<<NN, D2/2, 0, stream>>>(offs, srcs, (const float2*)as2, (const float2*)ad2,
                                     (const unsigned int*)hx2b, bias2, out2);
  k_bnstats<D2><<<200, D2, 0, stream>>>(out2, bns2, bnq2);
  k_bnapply<D2><<<(NN*D2)/TB, TB, 0, stream>>>(out2, bns2, bnq2, gamma2, beta2, (float*)d_out);
}